// Round 7
// baseline (223.556 us; speedup 1.0000x reference)
//
#include <hip/hip_runtime.h>

// SSIM 3D loss: pred/target f32 [4,1,64,192,192], scalar 1 - mean(ssim_map).
// v6: A = fused W+H blur; interm packed 2xfp16/u32 (IPITCH 25 vs 8-way bank
//        conflicts), H phase split into two 16-row halves (2 cols/task),
//        dwordx4 store of pixel-pair X. Outputs X=[4 fields fp16] + Y=pt.
//     B = D blur, 2 adjacent columns per thread (b128+b32 per plane),
//        modular sliding window with literal slots. SSIM + partial sums.
//     C = finalize.

#define D_DIM 64
#define H_DIM 192
#define W_DIM 192
#define SLICE (H_DIM * W_DIM)   // 36864
#define VOL   (D_DIM * SLICE)   // 2359296
#define NB    4
#define KS    11
#define RAD   5
#define TH    32
#define TW    48
#define HT    (TH + 2 * RAD)    // 42 halo rows
#define WTT   (TW + 2 * RAD)    // 58 halo cols
#define SPITCH 59               // staging pitch (fp32)
#define IP32  25                // interm pitch in u32 pairs (banks spread)
#define IPF32 (HT * IP32)       // 1050 u32 per field
#define C1F   (0.01f * 0.01f)
#define C2F   (0.03f * 0.03f)

typedef _Float16 h2v __attribute__((ext_vector_type(2)));
typedef _Float16 h8v __attribute__((ext_vector_type(8)));

__device__ __forceinline__ void make_window(float* g) {
    float s = 0.f;
#pragma unroll
    for (int i = 0; i < KS; ++i) {
        float c = (float)(i - RAD);
        g[i] = expf(-(c * c) * (1.0f / 4.5f));  // 2*sigma^2 = 4.5
        s += g[i];
    }
    float inv = 1.0f / s;
#pragma unroll
    for (int i = 0; i < KS; ++i) g[i] *= inv;
}

__device__ __forceinline__ unsigned pk(float a, float b) {
    unsigned lo = __builtin_bit_cast(unsigned short, (_Float16)a);
    unsigned hi = __builtin_bit_cast(unsigned short, (_Float16)b);
    return lo | (hi << 16);
}

// ---- Kernel A: W+H blur of 5 derived fields for one (b,d) slice tile ----
__global__ __launch_bounds__(256) void hw_blur_kernel(
    const float* __restrict__ pred, const float* __restrict__ targ,
    uint2* __restrict__ Xg, unsigned short* __restrict__ Yg, int b0) {
    __shared__ union U {
        float stage[2 * HT * SPITCH];            // 19824 B: sp | st
        unsigned obuf32[5 * TH * (TW / 2)];      // 15360 B, reused after W
    } u;
    __shared__ unsigned interm32[5 * IPF32];     // 21000 B
    float* sp = u.stage;
    float* st = u.stage + HT * SPITCH;

    float g[KS];
    make_window(g);

    const int tid = threadIdx.x;
    const int d    = blockIdx.y;
    const int tile = blockIdx.x;              // 0..23
    const int h0 = (tile >> 2) * TH;          // 6 tiles in H
    const int w0 = (tile & 3) * TW;           // 4 tiles in W
    const int bl = blockIdx.z;

    const int in_base = (b0 + bl) * VOL + d * SLICE;

    // ---- Stage p/t halo tiles (zero-padded at H/W edges and pad col) ----
    for (int i = tid; i < HT * SPITCH; i += 256) {
        int y = i / SPITCH, x = i - y * SPITCH;
        int gh = h0 + y - RAD, gw = w0 + x - RAD;
        float pv = 0.f, tv = 0.f;
        if (x < WTT && (unsigned)gh < (unsigned)H_DIM && (unsigned)gw < (unsigned)W_DIM) {
            int idx = in_base + gh * W_DIM + gw;
            pv = pred[idx];
            tv = targ[idx];
        }
        sp[i] = pv;
        st[i] = tv;
    }
    __syncthreads();

    // ---- Phase W: register-window blur along W, derive 5 fields ----
    // 252 tasks: y in [0,42) halo rows x 6 segments of 8 outputs.
    // Output pairs (o, o+1) packed into one u32 write per field.
    if (tid < 252) {
        const int y = tid / 6;
        const int x0 = (tid % 6) * 8;
        float wp[18], wt[18];
#pragma unroll
        for (int k = 0; k < 18; ++k) {
            wp[k] = sp[y * SPITCH + x0 + k];
            wt[k] = st[y * SPITCH + x0 + k];
        }
        const int ib = y * IP32 + (x0 >> 1);
#pragma unroll
        for (int o = 0; o < 8; o += 2) {
            float r0[2], r1[2], r2[2], r3[2], r4[2];
#pragma unroll
            for (int c = 0; c < 2; ++c) {
                float s0 = 0.f, s1 = 0.f, s2 = 0.f, s3 = 0.f, s4 = 0.f;
#pragma unroll
                for (int k = 0; k < KS; ++k) {
                    float pv = wp[o + c + k], tv = wt[o + c + k], gk = g[k];
                    s0 += gk * pv;
                    s1 += gk * tv;
                    s2 += gk * pv * pv;
                    s3 += gk * tv * tv;
                    s4 += gk * pv * tv;
                }
                r0[c] = s0; r1[c] = s1; r2[c] = s2; r3[c] = s3; r4[c] = s4;
            }
            int idx = ib + (o >> 1);
            interm32[0 * IPF32 + idx] = pk(r0[0], r0[1]);
            interm32[1 * IPF32 + idx] = pk(r1[0], r1[1]);
            interm32[2 * IPF32 + idx] = pk(r2[0], r2[1]);
            interm32[3 * IPF32 + idx] = pk(r3[0], r3[1]);
            interm32[4 * IPF32 + idx] = pk(r4[0], r4[1]);
        }
    }
    __syncthreads();

    // ---- Phase H: accumulator-trick blur along H, split into 2 halves ----
    // 240 tasks: f in [0,5) x half hh in [0,2) x column-pair p in [0,24).
    // Each task: 26 halo rows -> 16 outputs, 2 columns at once (u32 reads).
    // Row yy (local) feeds slots (yy+m+1)%11 with g[10-m]; ramp-in guard
    // skips m < 10-yy for yy < 10 (those outputs belong to y<start).
    if (tid < 240) {
        const int f  = tid / 48;
        const int r  = tid % 48;
        const int hh = r / 24;
        const int p  = r % 24;
        const unsigned* col = interm32 + f * IPF32 + (hh * 16) * IP32 + p;
        unsigned* ob = u.obuf32 + f * (TH * (TW / 2)) + (hh * 16) * (TW / 2) + p;
        float acc0[KS], acc1[KS];
#pragma unroll
        for (int s = 0; s < KS; ++s) { acc0[s] = 0.f; acc1[s] = 0.f; }
#pragma unroll
        for (int yy = 0; yy < 26; ++yy) {
            h2v hv = __builtin_bit_cast(h2v, col[yy * IP32]);
            float v0 = (float)hv[0], v1 = (float)hv[1];
#pragma unroll
            for (int m = 0; m < KS; ++m) {
                if (yy < 10 && m < 10 - yy) continue;   // folds at compile time
                const int s = (yy + m + 1) % KS;
                acc0[s] += g[10 - m] * v0;
                acc1[s] += g[10 - m] * v1;
            }
            if (yy >= 10) {
                const int s = (yy + 1) % KS;
                ob[(yy - 10) * (TW / 2)] = pk(acc0[s], acc1[s]);
                acc0[s] = 0.f; acc1[s] = 0.f;
            }
        }
    }
    __syncthreads();

    // ---- Store phase: pixel-pairs -> one dwordx4 X store + dword Y ----
    const size_t pl_base = (size_t)(bl * D_DIM + d) * SLICE;
#pragma unroll
    for (int it = 0; it < 3; ++it) {              // 768 pairs / 256 threads
        int pr = it * 256 + tid;                  // pair index
        int y = pr / 24, xp = pr % 24;
        unsigned a0 = u.obuf32[0 * 768 + pr];
        unsigned a1 = u.obuf32[1 * 768 + pr];
        unsigned a2 = u.obuf32[2 * 768 + pr];
        unsigned a3 = u.obuf32[3 * 768 + pr];
        unsigned a4 = u.obuf32[4 * 768 + pr];
        size_t gi = pl_base + (size_t)(h0 + y) * W_DIM + (w0 + 2 * xp);
        uint4 xv = make_uint4((a0 & 0xffffu) | (a1 << 16),
                              (a2 & 0xffffu) | (a3 << 16),
                              (a0 >> 16) | (a1 & 0xffff0000u),
                              (a2 >> 16) | (a3 & 0xffff0000u));
        *(uint4*)(Xg + gi) = xv;
        *(unsigned*)(Yg + gi) = a4;
    }
}

// ================= Kernel B: D blur + SSIM + partial sums =================
// 2 adjacent columns per thread. Modular sliding window: slot s holds plane
// p with p%11 == s among the last 11 loaded. All slot indices literal.

#define LOADP(s, q) do {                                                  \
    h8v _v = x8[(q) * (SLICE / 2)];                                       \
    h2v _y = __builtin_bit_cast(h2v, y2[(q) * (SLICE / 2)]);              \
    wa0[s] = (float)_v[0]; wa1[s] = (float)_v[1];                         \
    wa2[s] = (float)_v[2]; wa3[s] = (float)_v[3];                         \
    wb0[s] = (float)_v[4]; wb1[s] = (float)_v[5];                         \
    wb2[s] = (float)_v[6]; wb3[s] = (float)_v[7];                         \
    wa4[s] = (float)_y[0]; wb4[s] = (float)_y[1];                         \
} while (0)

#define SSIM_ACC(MP, MT, E2, T2, PT) do {                                 \
    float _mps = (MP) * (MP), _mts = (MT) * (MT), _mpt = (MP) * (MT);     \
    float _num = (2.f * _mpt + C1F) * (2.f * ((PT) - _mpt) + C2F);        \
    float _den = (_mps + _mts + C1F) *                                    \
                 (((E2) - _mps) + ((T2) - _mts) + C2F);                   \
    ssim_sum += _num * __builtin_amdgcn_rcpf(_den);                       \
} while (0)

// emit output d with r = (d-6) mod 11: window slots (1+r+j)%11, j=0..JHI
#define EMIT_W(r, JHI) do {                                               \
    float _ap = 0.f, _at = 0.f, _a2 = 0.f, _a3 = 0.f, _a4 = 0.f;          \
    float _bp = 0.f, _bt = 0.f, _b2 = 0.f, _b3 = 0.f, _b4 = 0.f;          \
    _Pragma("unroll")                                                     \
    for (int _j = 0; _j <= (JHI); ++_j) {                                 \
        const int _s = (1 + (r) + _j) % 11; const float _g = g[_j];       \
        _ap += _g * wa0[_s]; _at += _g * wa1[_s]; _a2 += _g * wa2[_s];    \
        _a3 += _g * wa3[_s]; _a4 += _g * wa4[_s];                         \
        _bp += _g * wb0[_s]; _bt += _g * wb1[_s]; _b2 += _g * wb2[_s];    \
        _b3 += _g * wb3[_s]; _b4 += _g * wb4[_s];                         \
    }                                                                     \
    SSIM_ACC(_ap, _at, _a2, _a3, _a4);                                    \
    SSIM_ACC(_bp, _bt, _b2, _b3, _b4);                                    \
} while (0)

// ramp-in emit for output d in [0,5]: planes 0..d+5 at slot = plane
#define EMIT_IN(d) do {                                                   \
    float _ap = 0.f, _at = 0.f, _a2 = 0.f, _a3 = 0.f, _a4 = 0.f;          \
    float _bp = 0.f, _bt = 0.f, _b2 = 0.f, _b3 = 0.f, _b4 = 0.f;          \
    _Pragma("unroll")                                                     \
    for (int _j = 5 - (d); _j < 11; ++_j) {                               \
        const int _s = (d) - 5 + _j; const float _g = g[_j];              \
        _ap += _g * wa0[_s]; _at += _g * wa1[_s]; _a2 += _g * wa2[_s];    \
        _a3 += _g * wa3[_s]; _a4 += _g * wa4[_s];                         \
        _bp += _g * wb0[_s]; _bt += _g * wb1[_s]; _b2 += _g * wb2[_s];    \
        _b3 += _g * wb3[_s]; _b4 += _g * wb4[_s];                         \
    }                                                                     \
    SSIM_ACC(_ap, _at, _a2, _a3, _a4);                                    \
    SSIM_ACC(_bp, _bt, _b2, _b3, _b4);                                    \
} while (0)

#define STEP(r, q) do { LOADP(r, q); EMIT_W(r, 10); } while (0)

__global__ __launch_bounds__(256) void dblur_ssim_kernel(
    const uint2* __restrict__ Xg, const unsigned short* __restrict__ Yg,
    float* __restrict__ partials) {
    float g[KS];
    make_window(g);

    const int tid = threadIdx.x;
    const int bl = blockIdx.x / 72;                    // local batch
    const int hw0 = (blockIdx.x % 72) * 512 + tid * 2; // column pair
    const int cb = bl * VOL + hw0;
    const h8v* x8 = (const h8v*)Xg + (cb >> 1);
    const unsigned* y2 = (const unsigned*)Yg + (cb >> 1);

    float wa0[KS], wa1[KS], wa2[KS], wa3[KS], wa4[KS];
    float wb0[KS], wb1[KS], wb2[KS], wb3[KS], wb4[KS];
    float ssim_sum = 0.f;

    if (blockIdx.y == 0) {
        // ---- outputs d = 0..31, planes 0..36 ----
        LOADP(0, 0); LOADP(1, 1); LOADP(2, 2); LOADP(3, 3); LOADP(4, 4);
        LOADP(5, 5); LOADP(6, 6); LOADP(7, 7); LOADP(8, 8); LOADP(9, 9);
        LOADP(10, 10);
        EMIT_IN(0); EMIT_IN(1); EMIT_IN(2); EMIT_IN(3); EMIT_IN(4); EMIT_IN(5);
#pragma unroll 1
        for (int b = 0; b < 2; ++b) {                 // d = 6..27
            const int qb = 11 + 11 * b;
            STEP(0, qb + 0); STEP(1, qb + 1); STEP(2, qb + 2); STEP(3, qb + 3);
            STEP(4, qb + 4); STEP(5, qb + 5); STEP(6, qb + 6); STEP(7, qb + 7);
            STEP(8, qb + 8); STEP(9, qb + 9); STEP(10, qb + 10);
        }
        // d = 28..31: planes 33..36
        STEP(0, 33); STEP(1, 34); STEP(2, 35); STEP(3, 36);
    } else {
        // ---- outputs d = 32..63, planes 27..63 ----
        // preload planes 27..37 at slot plane%11
        LOADP(5, 27); LOADP(6, 28); LOADP(7, 29); LOADP(8, 30); LOADP(9, 31);
        LOADP(10, 32); LOADP(0, 33); LOADP(1, 34); LOADP(2, 35); LOADP(3, 36);
        LOADP(4, 37);
        EMIT_W(4, 10);                                // d = 32 (planes 27..37)
        // d = 33..38: planes 38..43
        STEP(5, 38); STEP(6, 39); STEP(7, 40); STEP(8, 41); STEP(9, 42);
        STEP(10, 43);
#pragma unroll 1
        for (int b = 0; b < 1; ++b) {                 // d = 39..49: planes 44..54
            const int qb = 44;
            STEP(0, qb + 0); STEP(1, qb + 1); STEP(2, qb + 2); STEP(3, qb + 3);
            STEP(4, qb + 4); STEP(5, qb + 5); STEP(6, qb + 6); STEP(7, qb + 7);
            STEP(8, qb + 8); STEP(9, qb + 9); STEP(10, qb + 10);
        }
        // d = 50..58: planes 55..63
        STEP(0, 55); STEP(1, 56); STEP(2, 57); STEP(3, 58); STEP(4, 59);
        STEP(5, 60); STEP(6, 61); STEP(7, 62); STEP(8, 63);
        // ramp-out d = 59..63 (truncated windows, no loads)
        EMIT_W(9, 9); EMIT_W(10, 8); EMIT_W(11, 7); EMIT_W(12, 6); EMIT_W(13, 5);
    }

    // block reduction
    float a = ssim_sum;
#pragma unroll
    for (int off = 32; off > 0; off >>= 1) a += __shfl_down(a, off, 64);
    __shared__ float red[4];
    int lane = tid & 63, wv = tid >> 6;
    if (lane == 0) red[wv] = a;
    __syncthreads();
    if (tid == 0)
        partials[blockIdx.y * gridDim.x + blockIdx.x] =
            red[0] + red[1] + red[2] + red[3];
}

// ---- Kernel C: final reduction ----
__global__ __launch_bounds__(256) void finalize_kernel(
    const float* __restrict__ partials, int n, float* __restrict__ out) {
    double a = 0.0;
    for (int i = threadIdx.x; i < n; i += 256) a += (double)partials[i];
#pragma unroll
    for (int off = 32; off > 0; off >>= 1) a += __shfl_down(a, off, 64);
    __shared__ double red[4];
    int lane = threadIdx.x & 63, wv = threadIdx.x >> 6;
    if (lane == 0) red[wv] = a;
    __syncthreads();
    if (threadIdx.x == 0) {
        double s = red[0] + red[1] + red[2] + red[3];
        out[0] = (float)(1.0 - s / (double)((long long)NB * VOL));
    }
}

extern "C" void kernel_launch(void* const* d_in, const int* in_sizes, int n_in,
                              void* d_out, int out_size, void* d_ws, size_t ws_size,
                              hipStream_t stream) {
    const float* pred = (const float*)d_in[0];
    const float* targ = (const float*)d_in[1];
    float* out = (float*)d_out;

    // batches per chunk G in {4,2,1}: X (8B/px) + Y (2B/px) + partials
    int G = 4;
    while (G > 1 && (size_t)G * VOL * 10 + 8192 > ws_size) G >>= 1;

    uint2* Xg = (uint2*)d_ws;
    unsigned short* Yg = (unsigned short*)((char*)d_ws + (size_t)G * VOL * 8);
    float* partials = (float*)((char*)d_ws + (size_t)G * VOL * 10);
    const int bpc = G * 72;                    // dblur blocks per (chunk, half)
    const int nchunks = NB / G;

    for (int c = 0; c < nchunks; ++c) {
        hw_blur_kernel<<<dim3(24, D_DIM, G), 256, 0, stream>>>(
            pred, targ, Xg, Yg, c * G);
        dblur_ssim_kernel<<<dim3(bpc, 2), 256, 0, stream>>>(
            Xg, Yg, partials + c * 2 * bpc);
    }
    finalize_kernel<<<1, 256, 0, stream>>>(partials, NB * 144, out);
}